// Round 15
// baseline (250.465 us; speedup 1.0000x reference)
//
#include <hip/hip_runtime.h>

// GCN 3-layer. v15: v14 + 128-node buckets (halves partition's fragmented
// write line-touches + claims) + 16ch-padded layer-3 table (uint2 gathers).

constexpr int BK_SHIFT = 7;               // 128 nodes per bucket
constexpr int BK_NODES = 128;
constexpr int BK_CAP   = 4688;            // mean 4096 + ~9 sigma
constexpr int MAXNB    = 784;

typedef __attribute__((ext_vector_type(8))) short short8_t;   // 8 bf16
typedef __attribute__((ext_vector_type(4))) float f32x4_t;    // acc frag

__device__ __forceinline__ unsigned short f2bf(float f) {
    unsigned u = __builtin_bit_cast(unsigned, f);
    u += 0x7FFF + ((u >> 16) & 1);        // round to nearest even
    return (unsigned short)(u >> 16);
}
__device__ __forceinline__ unsigned pack2(float lo, float hi) {
    return (unsigned)f2bf(lo) | ((unsigned)f2bf(hi) << 16);
}
__device__ __forceinline__ float bf_lo(unsigned d) {
    return __builtin_bit_cast(float, d << 16);
}
__device__ __forceinline__ float bf_hi(unsigned d) {
    return __builtin_bit_cast(float, d & 0xFFFF0000u);
}
__device__ __forceinline__ float bf1(unsigned short u) {
    return __builtin_bit_cast(float, (unsigned)u << 16);
}

// 512 thr, 16384 edges/block. Single LDS-atomic pass: rank = atomic return.
// meta = bucket(11b) | rank<<11. cursor[] relative (memset-0).
__global__ __launch_bounds__(512) void k_partition(const int* __restrict__ src,
                            const int* __restrict__ dst,
                            int E, int nb, int* __restrict__ cursor,
                            unsigned* __restrict__ inter) {
    __shared__ int lcount[MAXNB];
    __shared__ int gbase[MAXNB];
    int t = threadIdx.x;
    int base = blockIdx.x * 16384;
    for (int i = t; i < MAXNB; i += 512) lcount[i] = 0;
    __syncthreads();
    unsigned rec[32];
    unsigned meta[32];
    int rem = E - base;
    if (rem >= 16384) {                   // fast path: full tile, int4 loads
        const int4* src4 = reinterpret_cast<const int4*>(src + base);
        const int4* dst4 = reinterpret_cast<const int4*>(dst + base);
#pragma unroll
        for (int j = 0; j < 8; j++) {
            int4 s4 = src4[j * 512 + t];
            int4 d4 = dst4[j * 512 + t];
            int ss[4] = {s4.x, s4.y, s4.z, s4.w};
            int dd[4] = {d4.x, d4.y, d4.z, d4.w};
#pragma unroll
            for (int k = 0; k < 4; k++) {
                int b = dd[k] >> BK_SHIFT;
                int r = atomicAdd(&lcount[b], 1);
                rec[j * 4 + k] = (unsigned)ss[k] | ((unsigned)(dd[k] & (BK_NODES - 1)) << 20);
                meta[j * 4 + k] = (unsigned)b | ((unsigned)r << 11);
            }
        }
    } else {                              // tail block: scalar with guards
#pragma unroll
        for (int j = 0; j < 32; j++) {
            int idx = base + j * 512 + t;
            if (idx < E) {
                int s = src[idx], d = dst[idx];
                int b = d >> BK_SHIFT;
                int r = atomicAdd(&lcount[b], 1);
                rec[j] = (unsigned)s | ((unsigned)(d & (BK_NODES - 1)) << 20);
                meta[j] = (unsigned)b | ((unsigned)r << 11);
            } else meta[j] = 0xFFFFFFFFu;
        }
    }
    __syncthreads();
    for (int i = t; i < nb; i += 512) {
        int c = lcount[i];
        gbase[i] = c ? atomicAdd(&cursor[i], c) : 0;
    }
    __syncthreads();
    if (rem >= 16384) {
#pragma unroll
        for (int j = 0; j < 32; j++) {
            int b = meta[j] & 2047;
            int pos = gbase[b] + (int)(meta[j] >> 11);
            if (pos < BK_CAP) inter[(size_t)b * BK_CAP + pos] = rec[j];
        }
    } else {
#pragma unroll
        for (int j = 0; j < 32; j++) {
            if (meta[j] != 0xFFFFFFFFu) {
                int b = meta[j] & 2047;
                int pos = gbase[b] + (int)(meta[j] >> 11);
                if (pos < BK_CAP) inter[(size_t)b * BK_CAP + pos] = rec[j];
            }
        }
    }
}

// per-bucket counting sort -> srt/offs/dinv (done ONCE, reused by all aggs)
__global__ __launch_bounds__(512) void k_sort(const unsigned* __restrict__ inter,
                        const int* __restrict__ cursor,
                        unsigned* __restrict__ srt_g, int* __restrict__ offs_g,
                        float* __restrict__ dinv, int N) {
    __shared__ unsigned raw[BK_CAP];
    __shared__ unsigned srt[BK_CAP];
    __shared__ int hist[BK_NODES];
    __shared__ int tmp[BK_NODES];
    __shared__ int offs[BK_NODES + 1];
    __shared__ int cur[BK_NODES];
    int t = threadIdx.x, b = blockIdx.x;
    if (t < BK_NODES) hist[t] = 0;
    __syncthreads();
    int cnt = min(cursor[b], BK_CAP);
    const unsigned* ip = inter + (size_t)b * BK_CAP;
    int c4 = cnt & ~3;
    for (int i = t * 4; i < c4; i += 2048) {
        uint4 r4 = *reinterpret_cast<const uint4*>(ip + i);
        *reinterpret_cast<uint4*>(&raw[i]) = r4;
        atomicAdd(&hist[r4.x >> 20], 1);
        atomicAdd(&hist[r4.y >> 20], 1);
        atomicAdd(&hist[r4.z >> 20], 1);
        atomicAdd(&hist[r4.w >> 20], 1);
    }
    for (int i = c4 + t; i < cnt; i += 512) {
        unsigned r = ip[i];
        raw[i] = r;
        atomicAdd(&hist[r >> 20], 1);
    }
    __syncthreads();
    // 128-bin inclusive scan (all threads hit the barriers)
    if (t < BK_NODES) tmp[t] = hist[t];
    __syncthreads();
    for (int st = 1; st < BK_NODES; st <<= 1) {
        int v = 0;
        if (t < BK_NODES && t >= st) v = tmp[t - st];
        __syncthreads();
        if (t < BK_NODES) tmp[t] += v;
        __syncthreads();
    }
    if (t < BK_NODES) {
        offs[t + 1] = tmp[t];
        if (t == 0) offs[0] = 0;
        cur[t] = tmp[t] - hist[t];
        int d = b * BK_NODES + t;
        if (d < N) dinv[d] = rsqrtf((float)(hist[t] + 1));
    }
    __syncthreads();
    for (int i = t; i < cnt; i += 512) {
        unsigned r = raw[i];
        int pos = atomicAdd(&cur[r >> 20], 1);
        srt[pos] = r & 0xFFFFFu;
    }
    __syncthreads();
    unsigned* sg = srt_g + (size_t)b * BK_CAP;
    for (int i = t * 4; i < c4; i += 2048)
        *reinterpret_cast<uint4*>(sg + i) = *reinterpret_cast<const uint4*>(&srt[i]);
    for (int i = c4 + t; i < cnt; i += 512) sg[i] = srt[i];
    if (t < BK_NODES + 1) offs_g[b * (BK_NODES + 1) + t] = offs[t];
}

// ---- MFMA GEMM: Hs_bf16[n,64] = dinv[n]*(X[n,K] @ W[K,64]), row-major out
template <int K, bool IN_F32>
__global__ __launch_bounds__(256) void k_gemmMF(const void* __restrict__ Xv,
                           const float* __restrict__ W,
                           const float* __restrict__ dinv,
                           unsigned short* __restrict__ Y, int n) {
    constexpr int KP = K + 8;
    __shared__ unsigned short Al[64 * KP];
    __shared__ unsigned short Bl[64 * KP];
    int t = threadIdx.x;
    int nb = blockIdx.x * 64;
    if (IN_F32) {
        const float* X = (const float*)Xv;
        for (int i = t * 4; i < 64 * K; i += 1024) {
            int r = i / K, c = i % K;
            int node = nb + r;
            float4 v = {0.f, 0.f, 0.f, 0.f};
            if (node < n) v = *reinterpret_cast<const float4*>(X + (size_t)node * K + c);
            uint2 pk = {pack2(v.x, v.y), pack2(v.z, v.w)};
            *reinterpret_cast<uint2*>(&Al[r * KP + c]) = pk;
        }
    } else {
        const unsigned short* X = (const unsigned short*)Xv;
        for (int i = t * 4; i < 64 * K; i += 1024) {
            int r = i / K, c = i % K;
            int node = nb + r;
            uint2 pk = {0u, 0u};
            if (node < n) pk = *reinterpret_cast<const uint2*>(X + (size_t)node * K + c);
            *reinterpret_cast<uint2*>(&Al[r * KP + c]) = pk;
        }
    }
    {
        int c = t & 63, kb = t >> 6;
        for (int k = kb; k < K; k += 4)
            Bl[c * KP + k] = f2bf(W[k * 64 + c]);
    }
    __syncthreads();
    int w = t >> 6, lane = t & 63;
    int ml = lane & 15, kg = lane >> 4;
    f32x4_t acc[4] = {{0,0,0,0},{0,0,0,0},{0,0,0,0},{0,0,0,0}};
    for (int ks = 0; ks < K / 32; ks++) {
        int ko = ks * 32 + kg * 8;
        short8_t a = *reinterpret_cast<const short8_t*>(&Al[(16 * w + ml) * KP + ko]);
#pragma unroll
        for (int c = 0; c < 4; c++) {
            short8_t b = *reinterpret_cast<const short8_t*>(&Bl[(16 * c + ml) * KP + ko]);
            acc[c] = __builtin_amdgcn_mfma_f32_16x16x32_bf16(a, b, acc[c], 0, 0, 0);
        }
    }
#pragma unroll
    for (int r = 0; r < 4; r++) {
        int grow = nb + 16 * w + kg * 4 + r;
        if (grow < n) {
            float dv = dinv[grow];
#pragma unroll
            for (int c = 0; c < 4; c++)
                Y[(size_t)grow * 64 + 16 * c + ml] = f2bf(dv * acc[c][r]);
        }
    }
}

// ---- GEMM: Hs10_bf16[n,16] = bf16(dinv[n]*(X[n,64] @ W[64,10])), 16ch pad
__global__ void k_gemm10(const float* __restrict__ X, const float* __restrict__ W,
                         const float* __restrict__ dinv, unsigned short* __restrict__ Y, int n) {
    __shared__ float ws[64 * 10];
    __shared__ float xs[16 * 64];
    int t = threadIdx.x;
    for (int i = t; i < 640; i += 256) ws[i] = W[i];
    int nb = blockIdx.x * 16;
    for (int i = t; i < 16 * 64; i += 256) {
        int r = i >> 6, c = i & 63;
        int node = nb + r;
        xs[i] = (node < n) ? X[(size_t)node * 64 + c] : 0.f;
    }
    __syncthreads();
    int ns = t >> 4, c = t & 15;
    int node = nb + ns;
    if (node < n) {
        unsigned short o = 0;
        if (c < 10) {
            float acc = 0.f;
            for (int k = 0; k < 64; k++) acc += xs[ns * 64 + k] * ws[k * 10 + c];
            o = f2bf(dinv[node] * acc);
        }
        Y[(size_t)node * 16 + c] = o;
    }
}

// ---- agg 64ch, row-major table, presorted input, 2-deep unroll.
template <int OBF>
__global__ __launch_bounds__(512) void k_agg64(const unsigned short* __restrict__ H,
                        const unsigned* __restrict__ srt_g, const int* __restrict__ offs_g,
                        const float* __restrict__ dinv, const float* __restrict__ bias,
                        void* __restrict__ outv, int N, int relu) {
    __shared__ unsigned srt[BK_CAP];
    __shared__ int offs[BK_NODES + 1];
    int t = threadIdx.x, b = blockIdx.x;
    if (t < BK_NODES + 1) offs[t] = offs_g[b * (BK_NODES + 1) + t];
    __syncthreads();
    int cnt = offs[BK_NODES];
    const unsigned* sg = srt_g + (size_t)b * BK_CAP;
    int c4 = cnt & ~3;
    for (int i = t * 4; i < c4; i += 2048)
        *reinterpret_cast<uint4*>(&srt[i]) = *reinterpret_cast<const uint4*>(sg + i);
    for (int i = c4 + t; i < cnt; i += 512) srt[i] = sg[i];
    __syncthreads();
    int wv = t >> 6, lane = t & 63;
    int esub = lane >> 3, cg = lane & 7;  // 8 edge slots x 8 channel groups
    const unsigned short* Hc = H + (cg << 3);
    for (int nd = wv; nd < BK_NODES; nd += 8) {
        int d = b * BK_NODES + nd;
        if (d >= N) break;
        int o0 = offs[nd], o1 = offs[nd + 1];
        uint4 sv = {0, 0, 0, 0};
        float dv = 0.f;
        if (esub == 0) {                  // hoisted self-row + dinv
            sv = *reinterpret_cast<const uint4*>(Hc + ((size_t)d << 6));
            dv = dinv[d];
        }
        float a0 = 0.f, a1 = 0.f, a2 = 0.f, a3 = 0.f;
        float a4 = 0.f, a5 = 0.f, a6 = 0.f, a7 = 0.f;
        int e = o0 + esub;
        for (; e + 8 < o1; e += 16) {     // two independent gathers in flight
            int s0 = srt[e], s1 = srt[e + 8];
            const uint4 v0 = *reinterpret_cast<const uint4*>(Hc + ((size_t)s0 << 6));
            const uint4 v1 = *reinterpret_cast<const uint4*>(Hc + ((size_t)s1 << 6));
            a0 += bf_lo(v0.x); a1 += bf_hi(v0.x); a2 += bf_lo(v0.y); a3 += bf_hi(v0.y);
            a4 += bf_lo(v0.z); a5 += bf_hi(v0.z); a6 += bf_lo(v0.w); a7 += bf_hi(v0.w);
            a0 += bf_lo(v1.x); a1 += bf_hi(v1.x); a2 += bf_lo(v1.y); a3 += bf_hi(v1.y);
            a4 += bf_lo(v1.z); a5 += bf_hi(v1.z); a6 += bf_lo(v1.w); a7 += bf_hi(v1.w);
        }
        if (e < o1) {
            int s0 = srt[e];
            const uint4 v0 = *reinterpret_cast<const uint4*>(Hc + ((size_t)s0 << 6));
            a0 += bf_lo(v0.x); a1 += bf_hi(v0.x); a2 += bf_lo(v0.y); a3 += bf_hi(v0.y);
            a4 += bf_lo(v0.z); a5 += bf_hi(v0.z); a6 += bf_lo(v0.w); a7 += bf_hi(v0.w);
        }
#pragma unroll
        for (int m = 8; m <= 32; m <<= 1) {
            a0 += __shfl_xor(a0, m); a1 += __shfl_xor(a1, m);
            a2 += __shfl_xor(a2, m); a3 += __shfl_xor(a3, m);
            a4 += __shfl_xor(a4, m); a5 += __shfl_xor(a5, m);
            a6 += __shfl_xor(a6, m); a7 += __shfl_xor(a7, m);
        }
        if (esub == 0) {
            float s[8] = {bf_lo(sv.x), bf_hi(sv.x), bf_lo(sv.y), bf_hi(sv.y),
                          bf_lo(sv.z), bf_hi(sv.z), bf_lo(sv.w), bf_hi(sv.w)};
            float ac[8] = {a0, a1, a2, a3, a4, a5, a6, a7};
            const float* bp = bias + cg * 8;
            float o[8];
#pragma unroll
            for (int j = 0; j < 8; j++) {
                float val = dv * (ac[j] + s[j]) + bp[j];
                if (relu) val = fmaxf(val, 0.f);
                o[j] = val;
            }
            if (OBF) {
                unsigned short* op = (unsigned short*)outv + (size_t)d * 64 + cg * 8;
                uint4 pk = {pack2(o[0], o[1]), pack2(o[2], o[3]),
                            pack2(o[4], o[5]), pack2(o[6], o[7])};
                *reinterpret_cast<uint4*>(op) = pk;
            } else {
                float* op = (float*)outv + (size_t)d * 64 + cg * 8;
                float4 r0 = {o[0], o[1], o[2], o[3]}, r1 = {o[4], o[5], o[6], o[7]};
                *reinterpret_cast<float4*>(op)     = r0;
                *reinterpret_cast<float4*>(op + 4) = r1;
            }
        }
    }
}

// ---- agg 10ch (final, no relu): 16ch-padded bf16 table, uint2 gathers ----
__global__ __launch_bounds__(512) void k_agg10s(const unsigned short* __restrict__ H,
                        const unsigned* __restrict__ srt_g, const int* __restrict__ offs_g,
                        const float* __restrict__ dinv, const float* __restrict__ b3,
                        float* __restrict__ out, int N) {
    __shared__ unsigned srt[BK_CAP];
    __shared__ int offs[BK_NODES + 1];
    int t = threadIdx.x, b = blockIdx.x;
    if (t < BK_NODES + 1) offs[t] = offs_g[b * (BK_NODES + 1) + t];
    __syncthreads();
    int cnt = offs[BK_NODES];
    const unsigned* sg = srt_g + (size_t)b * BK_CAP;
    int c4 = cnt & ~3;
    for (int i = t * 4; i < c4; i += 2048)
        *reinterpret_cast<uint4*>(&srt[i]) = *reinterpret_cast<const uint4*>(sg + i);
    for (int i = c4 + t; i < cnt; i += 512) srt[i] = sg[i];
    __syncthreads();
    int wv = t >> 6, lane = t & 63;
    int es = lane >> 2, cg = lane & 3;    // 16 edge slots x 4 ch-groups (4ch ea)
    const unsigned short* Hc = H + cg * 4;
    for (int nd = wv; nd < BK_NODES; nd += 8) {
        int d = b * BK_NODES + nd;
        if (d >= N) break;
        int o0 = offs[nd], o1 = offs[nd + 1];
        uint2 sv = {0, 0};
        float dv = 0.f;
        if (es == 0) {
            sv = *reinterpret_cast<const uint2*>(Hc + (size_t)d * 16);
            dv = dinv[d];
        }
        float a0 = 0.f, a1 = 0.f, a2 = 0.f, a3 = 0.f;
        int e = o0 + es;
        for (; e + 16 < o1; e += 32) {    // two independent gathers in flight
            int s0 = srt[e], s1 = srt[e + 16];
            const uint2 v0 = *reinterpret_cast<const uint2*>(Hc + (size_t)s0 * 16);
            const uint2 v1 = *reinterpret_cast<const uint2*>(Hc + (size_t)s1 * 16);
            a0 += bf_lo(v0.x) + bf_lo(v1.x); a1 += bf_hi(v0.x) + bf_hi(v1.x);
            a2 += bf_lo(v0.y) + bf_lo(v1.y); a3 += bf_hi(v0.y) + bf_hi(v1.y);
        }
        if (e < o1) {
            int s0 = srt[e];
            const uint2 v0 = *reinterpret_cast<const uint2*>(Hc + (size_t)s0 * 16);
            a0 += bf_lo(v0.x); a1 += bf_hi(v0.x);
            a2 += bf_lo(v0.y); a3 += bf_hi(v0.y);
        }
#pragma unroll
        for (int m = 4; m <= 32; m <<= 1) {
            a0 += __shfl_xor(a0, m); a1 += __shfl_xor(a1, m);
            a2 += __shfl_xor(a2, m); a3 += __shfl_xor(a3, m);
        }
        if (es == 0) {
            float s[4] = {bf_lo(sv.x), bf_hi(sv.x), bf_lo(sv.y), bf_hi(sv.y)};
            float ac[4] = {a0, a1, a2, a3};
#pragma unroll
            for (int j = 0; j < 4; j++) {
                int ch = cg * 4 + j;
                if (ch < 10)
                    out[(size_t)d * 10 + ch] = dv * (ac[j] + s[j]) + b3[ch];
            }
        }
    }
}

extern "C" void kernel_launch(void* const* d_in, const int* in_sizes, int n_in,
                              void* d_out, int out_size, void* d_ws, size_t ws_size,
                              hipStream_t stream) {
    const float* x  = (const float*)d_in[0];
    const int*   ei = (const int*)d_in[1];
    const float* W1 = (const float*)d_in[2];
    const float* b1 = (const float*)d_in[3];
    const float* W2 = (const float*)d_in[4];
    const float* b2 = (const float*)d_in[5];
    const float* W3 = (const float*)d_in[6];
    const float* b3 = (const float*)d_in[7];

    int N = in_sizes[0] / 128;
    int E = in_sizes[1] / 2;
    const int* esrc = ei;
    const int* edst = ei + E;
    int nb = (N + BK_NODES - 1) >> BK_SHIFT;

    char* p = (char*)d_ws;
    auto carve = [&](size_t bytes) -> void* {
        void* r = p;
        p += (bytes + 255) & ~(size_t)255;
        return r;
    };
    int*      cursor = (int*)carve((size_t)MAXNB * 4);
    unsigned* inter  = (unsigned*)carve((size_t)nb * BK_CAP * 4);
    unsigned* srt_g  = (unsigned*)carve((size_t)nb * BK_CAP * 4);
    int*      offs_g = (int*)carve((size_t)nb * (BK_NODES + 1) * 4);
    float*    dinv   = (float*)carve((size_t)N * 4);
    unsigned short* Hs = (unsigned short*)carve((size_t)N * 64 * 2);  // bf16 row-major
    unsigned short* Gb = (unsigned short*)carve((size_t)N * 64 * 2);  // bf16 agg1 out
    float*    Gf     = (float*)carve((size_t)N * 64 * 4);             // f32 agg2 out
    unsigned short* Hs10 = (unsigned short*)carve((size_t)N * 16 * 2);
    (void)ws_size; (void)n_in; (void)out_size;

    hipMemsetAsync(cursor, 0, (size_t)nb * 4, stream);
    k_partition<<<(E + 16383) / 16384, 512, 0, stream>>>(esrc, edst, E, nb, cursor, inter);
    k_sort<<<nb, 512, 0, stream>>>(inter, cursor, srt_g, offs_g, dinv, N);

    // layer 1: Hs = bf16(dinv*(X @ W1)) ; Gb = bf16(relu(Agg(Hs)+b1))
    k_gemmMF<128, true><<<(N + 63) / 64, 256, 0, stream>>>(x, W1, dinv, Hs, N);
    k_agg64<1><<<nb, 512, 0, stream>>>(Hs, srt_g, offs_g, dinv, b1, Gb, N, 1);
    // layer 2: Hs = bf16(dinv*(Gb @ W2)) ; Gf = relu(Agg(Hs)+b2)
    k_gemmMF<64, false><<<(N + 63) / 64, 256, 0, stream>>>(Gb, W2, dinv, Hs, N);
    k_agg64<0><<<nb, 512, 0, stream>>>(Hs, srt_g, offs_g, dinv, b2, Gf, N, 1);
    // layer 3: Hs10 = bf16(dinv*(Gf @ W3)) 16ch-pad ; out = Agg(Hs10) + b3
    k_gemm10<<<(N + 15) / 16, 256, 0, stream>>>(Gf, W3, dinv, Hs10, N);
    k_agg10s<<<nb, 512, 0, stream>>>(Hs10, srt_g, offs_g, dinv, b3, (float*)d_out, N);
}

// Round 16
// 249.199 us; speedup vs baseline: 1.0051x; 1.0051x over previous
//
#include <hip/hip_runtime.h>

// GCN 3-layer. v16: v14 (64-node buckets — r15's 128-node bucket cost agg64
// occupancy and regressed) + v15's one independent win: 16ch-padded layer-3
// table with uint2 gathers.

constexpr int BK_SHIFT = 6;               // 64 nodes per bucket
constexpr int BK_NODES = 64;
constexpr int BK_CAP   = 2432;            // mean 2048 + 8.5 sigma
constexpr int MAXNB    = 1568;

typedef __attribute__((ext_vector_type(8))) short short8_t;   // 8 bf16
typedef __attribute__((ext_vector_type(4))) float f32x4_t;    // acc frag

__device__ __forceinline__ unsigned short f2bf(float f) {
    unsigned u = __builtin_bit_cast(unsigned, f);
    u += 0x7FFF + ((u >> 16) & 1);        // round to nearest even
    return (unsigned short)(u >> 16);
}
__device__ __forceinline__ unsigned pack2(float lo, float hi) {
    return (unsigned)f2bf(lo) | ((unsigned)f2bf(hi) << 16);
}
__device__ __forceinline__ float bf_lo(unsigned d) {
    return __builtin_bit_cast(float, d << 16);
}
__device__ __forceinline__ float bf_hi(unsigned d) {
    return __builtin_bit_cast(float, d & 0xFFFF0000u);
}
__device__ __forceinline__ float bf1(unsigned short u) {
    return __builtin_bit_cast(float, (unsigned)u << 16);
}

// 512 thr, 16384 edges/block. Single LDS-atomic pass: rank = atomic return.
// meta = bucket(11b) | rank<<11. cursor[] relative (memset-0).
__global__ __launch_bounds__(512) void k_partition(const int* __restrict__ src,
                            const int* __restrict__ dst,
                            int E, int nb, int* __restrict__ cursor,
                            unsigned* __restrict__ inter) {
    __shared__ int lcount[MAXNB];
    __shared__ int gbase[MAXNB];
    int t = threadIdx.x;
    int base = blockIdx.x * 16384;
    for (int i = t; i < MAXNB; i += 512) lcount[i] = 0;
    __syncthreads();
    unsigned rec[32];
    unsigned meta[32];
    int rem = E - base;
    if (rem >= 16384) {                   // fast path: full tile, int4 loads
        const int4* src4 = reinterpret_cast<const int4*>(src + base);
        const int4* dst4 = reinterpret_cast<const int4*>(dst + base);
#pragma unroll
        for (int j = 0; j < 8; j++) {
            int4 s4 = src4[j * 512 + t];
            int4 d4 = dst4[j * 512 + t];
            int ss[4] = {s4.x, s4.y, s4.z, s4.w};
            int dd[4] = {d4.x, d4.y, d4.z, d4.w};
#pragma unroll
            for (int k = 0; k < 4; k++) {
                int b = dd[k] >> BK_SHIFT;
                int r = atomicAdd(&lcount[b], 1);
                rec[j * 4 + k] = (unsigned)ss[k] | ((unsigned)(dd[k] & (BK_NODES - 1)) << 20);
                meta[j * 4 + k] = (unsigned)b | ((unsigned)r << 11);
            }
        }
    } else {                              // tail block: scalar with guards
#pragma unroll
        for (int j = 0; j < 32; j++) {
            int idx = base + j * 512 + t;
            if (idx < E) {
                int s = src[idx], d = dst[idx];
                int b = d >> BK_SHIFT;
                int r = atomicAdd(&lcount[b], 1);
                rec[j] = (unsigned)s | ((unsigned)(d & (BK_NODES - 1)) << 20);
                meta[j] = (unsigned)b | ((unsigned)r << 11);
            } else meta[j] = 0xFFFFFFFFu;
        }
    }
    __syncthreads();
    for (int i = t; i < nb; i += 512) {
        int c = lcount[i];
        gbase[i] = c ? atomicAdd(&cursor[i], c) : 0;
    }
    __syncthreads();
    if (rem >= 16384) {
#pragma unroll
        for (int j = 0; j < 32; j++) {
            int b = meta[j] & 2047;
            int pos = gbase[b] + (int)(meta[j] >> 11);
            if (pos < BK_CAP) inter[(size_t)b * BK_CAP + pos] = rec[j];
        }
    } else {
#pragma unroll
        for (int j = 0; j < 32; j++) {
            if (meta[j] != 0xFFFFFFFFu) {
                int b = meta[j] & 2047;
                int pos = gbase[b] + (int)(meta[j] >> 11);
                if (pos < BK_CAP) inter[(size_t)b * BK_CAP + pos] = rec[j];
            }
        }
    }
}

// per-bucket counting sort -> srt/offs/dinv (done ONCE, reused by all aggs)
__global__ __launch_bounds__(512) void k_sort(const unsigned* __restrict__ inter,
                        const int* __restrict__ cursor,
                        unsigned* __restrict__ srt_g, int* __restrict__ offs_g,
                        float* __restrict__ dinv, int N) {
    __shared__ unsigned raw[BK_CAP];
    __shared__ unsigned srt[BK_CAP];
    __shared__ int hist[BK_NODES];
    __shared__ int offs[BK_NODES + 1];
    __shared__ int cur[BK_NODES];
    int t = threadIdx.x, b = blockIdx.x;
    if (t < BK_NODES) hist[t] = 0;
    __syncthreads();
    int cnt = min(cursor[b], BK_CAP);
    const unsigned* ip = inter + (size_t)b * BK_CAP;
    int c4 = cnt & ~3;
    for (int i = t * 4; i < c4; i += 2048) {
        uint4 r4 = *reinterpret_cast<const uint4*>(ip + i);
        *reinterpret_cast<uint4*>(&raw[i]) = r4;
        atomicAdd(&hist[r4.x >> 20], 1);
        atomicAdd(&hist[r4.y >> 20], 1);
        atomicAdd(&hist[r4.z >> 20], 1);
        atomicAdd(&hist[r4.w >> 20], 1);
    }
    for (int i = c4 + t; i < cnt; i += 512) {
        unsigned r = ip[i];
        raw[i] = r;
        atomicAdd(&hist[r >> 20], 1);
    }
    __syncthreads();
    if (t < BK_NODES) {                   // wave 0: exclusive scan of 64 bins
        int v = hist[t];
        int inc = v;
#pragma unroll
        for (int d = 1; d < 64; d <<= 1) {
            int o = __shfl_up(inc, d);
            if (t >= d) inc += o;
        }
        offs[t + 1] = inc;
        if (t == 0) offs[0] = 0;
        cur[t] = inc - v;
        int d = b * BK_NODES + t;
        if (d < N) dinv[d] = rsqrtf((float)(v + 1));
    }
    __syncthreads();
    for (int i = t; i < cnt; i += 512) {
        unsigned r = raw[i];
        int pos = atomicAdd(&cur[r >> 20], 1);
        srt[pos] = r & 0xFFFFFu;
    }
    __syncthreads();
    unsigned* sg = srt_g + (size_t)b * BK_CAP;
    for (int i = t * 4; i < c4; i += 2048)
        *reinterpret_cast<uint4*>(sg + i) = *reinterpret_cast<const uint4*>(&srt[i]);
    for (int i = c4 + t; i < cnt; i += 512) sg[i] = srt[i];
    if (t < BK_NODES + 1) offs_g[b * (BK_NODES + 1) + t] = offs[t];
}

// ---- MFMA GEMM: Hs_bf16[n,64] = dinv[n]*(X[n,K] @ W[K,64]), row-major out
template <int K, bool IN_F32>
__global__ __launch_bounds__(256) void k_gemmMF(const void* __restrict__ Xv,
                           const float* __restrict__ W,
                           const float* __restrict__ dinv,
                           unsigned short* __restrict__ Y, int n) {
    constexpr int KP = K + 8;
    __shared__ unsigned short Al[64 * KP];
    __shared__ unsigned short Bl[64 * KP];
    int t = threadIdx.x;
    int nb = blockIdx.x * 64;
    if (IN_F32) {
        const float* X = (const float*)Xv;
        for (int i = t * 4; i < 64 * K; i += 1024) {
            int r = i / K, c = i % K;
            int node = nb + r;
            float4 v = {0.f, 0.f, 0.f, 0.f};
            if (node < n) v = *reinterpret_cast<const float4*>(X + (size_t)node * K + c);
            uint2 pk = {pack2(v.x, v.y), pack2(v.z, v.w)};
            *reinterpret_cast<uint2*>(&Al[r * KP + c]) = pk;
        }
    } else {
        const unsigned short* X = (const unsigned short*)Xv;
        for (int i = t * 4; i < 64 * K; i += 1024) {
            int r = i / K, c = i % K;
            int node = nb + r;
            uint2 pk = {0u, 0u};
            if (node < n) pk = *reinterpret_cast<const uint2*>(X + (size_t)node * K + c);
            *reinterpret_cast<uint2*>(&Al[r * KP + c]) = pk;
        }
    }
    {
        int c = t & 63, kb = t >> 6;
        for (int k = kb; k < K; k += 4)
            Bl[c * KP + k] = f2bf(W[k * 64 + c]);
    }
    __syncthreads();
    int w = t >> 6, lane = t & 63;
    int ml = lane & 15, kg = lane >> 4;
    f32x4_t acc[4] = {{0,0,0,0},{0,0,0,0},{0,0,0,0},{0,0,0,0}};
    for (int ks = 0; ks < K / 32; ks++) {
        int ko = ks * 32 + kg * 8;
        short8_t a = *reinterpret_cast<const short8_t*>(&Al[(16 * w + ml) * KP + ko]);
#pragma unroll
        for (int c = 0; c < 4; c++) {
            short8_t b = *reinterpret_cast<const short8_t*>(&Bl[(16 * c + ml) * KP + ko]);
            acc[c] = __builtin_amdgcn_mfma_f32_16x16x32_bf16(a, b, acc[c], 0, 0, 0);
        }
    }
#pragma unroll
    for (int r = 0; r < 4; r++) {
        int grow = nb + 16 * w + kg * 4 + r;
        if (grow < n) {
            float dv = dinv[grow];
#pragma unroll
            for (int c = 0; c < 4; c++)
                Y[(size_t)grow * 64 + 16 * c + ml] = f2bf(dv * acc[c][r]);
        }
    }
}

// ---- GEMM: Hs10_bf16[n,16] = bf16(dinv[n]*(X[n,64] @ W[64,10])), 16ch pad
__global__ void k_gemm10(const float* __restrict__ X, const float* __restrict__ W,
                         const float* __restrict__ dinv, unsigned short* __restrict__ Y, int n) {
    __shared__ float ws[64 * 10];
    __shared__ float xs[16 * 64];
    int t = threadIdx.x;
    for (int i = t; i < 640; i += 256) ws[i] = W[i];
    int nb = blockIdx.x * 16;
    for (int i = t; i < 16 * 64; i += 256) {
        int r = i >> 6, c = i & 63;
        int node = nb + r;
        xs[i] = (node < n) ? X[(size_t)node * 64 + c] : 0.f;
    }
    __syncthreads();
    int ns = t >> 4, c = t & 15;
    int node = nb + ns;
    if (node < n) {
        unsigned short o = 0;
        if (c < 10) {
            float acc = 0.f;
            for (int k = 0; k < 64; k++) acc += xs[ns * 64 + k] * ws[k * 10 + c];
            o = f2bf(dinv[node] * acc);
        }
        Y[(size_t)node * 16 + c] = o;
    }
}

// ---- agg 64ch, row-major table, presorted input, 2-deep unroll.
template <int OBF>
__global__ __launch_bounds__(512) void k_agg64(const unsigned short* __restrict__ H,
                        const unsigned* __restrict__ srt_g, const int* __restrict__ offs_g,
                        const float* __restrict__ dinv, const float* __restrict__ bias,
                        void* __restrict__ outv, int N, int relu) {
    __shared__ unsigned srt[BK_CAP];
    __shared__ int offs[BK_NODES + 1];
    int t = threadIdx.x, b = blockIdx.x;
    if (t < BK_NODES + 1) offs[t] = offs_g[b * (BK_NODES + 1) + t];
    __syncthreads();
    int cnt = offs[BK_NODES];
    const unsigned* sg = srt_g + (size_t)b * BK_CAP;
    int c4 = cnt & ~3;
    for (int i = t * 4; i < c4; i += 2048)
        *reinterpret_cast<uint4*>(&srt[i]) = *reinterpret_cast<const uint4*>(sg + i);
    for (int i = c4 + t; i < cnt; i += 512) srt[i] = sg[i];
    __syncthreads();
    int wv = t >> 6, lane = t & 63;
    int esub = lane >> 3, cg = lane & 7;  // 8 edge slots x 8 channel groups
    const unsigned short* Hc = H + (cg << 3);
    for (int nd = wv; nd < BK_NODES; nd += 8) {
        int d = b * BK_NODES + nd;
        if (d >= N) break;
        int o0 = offs[nd], o1 = offs[nd + 1];
        uint4 sv = {0, 0, 0, 0};
        float dv = 0.f;
        if (esub == 0) {                  // hoisted self-row + dinv
            sv = *reinterpret_cast<const uint4*>(Hc + ((size_t)d << 6));
            dv = dinv[d];
        }
        float a0 = 0.f, a1 = 0.f, a2 = 0.f, a3 = 0.f;
        float a4 = 0.f, a5 = 0.f, a6 = 0.f, a7 = 0.f;
        int e = o0 + esub;
        for (; e + 8 < o1; e += 16) {     // two independent gathers in flight
            int s0 = srt[e], s1 = srt[e + 8];
            const uint4 v0 = *reinterpret_cast<const uint4*>(Hc + ((size_t)s0 << 6));
            const uint4 v1 = *reinterpret_cast<const uint4*>(Hc + ((size_t)s1 << 6));
            a0 += bf_lo(v0.x); a1 += bf_hi(v0.x); a2 += bf_lo(v0.y); a3 += bf_hi(v0.y);
            a4 += bf_lo(v0.z); a5 += bf_hi(v0.z); a6 += bf_lo(v0.w); a7 += bf_hi(v0.w);
            a0 += bf_lo(v1.x); a1 += bf_hi(v1.x); a2 += bf_lo(v1.y); a3 += bf_hi(v1.y);
            a4 += bf_lo(v1.z); a5 += bf_hi(v1.z); a6 += bf_lo(v1.w); a7 += bf_hi(v1.w);
        }
        if (e < o1) {
            int s0 = srt[e];
            const uint4 v0 = *reinterpret_cast<const uint4*>(Hc + ((size_t)s0 << 6));
            a0 += bf_lo(v0.x); a1 += bf_hi(v0.x); a2 += bf_lo(v0.y); a3 += bf_hi(v0.y);
            a4 += bf_lo(v0.z); a5 += bf_hi(v0.z); a6 += bf_lo(v0.w); a7 += bf_hi(v0.w);
        }
#pragma unroll
        for (int m = 8; m <= 32; m <<= 1) {
            a0 += __shfl_xor(a0, m); a1 += __shfl_xor(a1, m);
            a2 += __shfl_xor(a2, m); a3 += __shfl_xor(a3, m);
            a4 += __shfl_xor(a4, m); a5 += __shfl_xor(a5, m);
            a6 += __shfl_xor(a6, m); a7 += __shfl_xor(a7, m);
        }
        if (esub == 0) {
            float s[8] = {bf_lo(sv.x), bf_hi(sv.x), bf_lo(sv.y), bf_hi(sv.y),
                          bf_lo(sv.z), bf_hi(sv.z), bf_lo(sv.w), bf_hi(sv.w)};
            float ac[8] = {a0, a1, a2, a3, a4, a5, a6, a7};
            const float* bp = bias + cg * 8;
            float o[8];
#pragma unroll
            for (int j = 0; j < 8; j++) {
                float val = dv * (ac[j] + s[j]) + bp[j];
                if (relu) val = fmaxf(val, 0.f);
                o[j] = val;
            }
            if (OBF) {
                unsigned short* op = (unsigned short*)outv + (size_t)d * 64 + cg * 8;
                uint4 pk = {pack2(o[0], o[1]), pack2(o[2], o[3]),
                            pack2(o[4], o[5]), pack2(o[6], o[7])};
                *reinterpret_cast<uint4*>(op) = pk;
            } else {
                float* op = (float*)outv + (size_t)d * 64 + cg * 8;
                float4 r0 = {o[0], o[1], o[2], o[3]}, r1 = {o[4], o[5], o[6], o[7]};
                *reinterpret_cast<float4*>(op)     = r0;
                *reinterpret_cast<float4*>(op + 4) = r1;
            }
        }
    }
}

// ---- agg 10ch (final, no relu): 16ch-padded bf16 table, uint2 gathers ----
__global__ __launch_bounds__(512) void k_agg10s(const unsigned short* __restrict__ H,
                        const unsigned* __restrict__ srt_g, const int* __restrict__ offs_g,
                        const float* __restrict__ dinv, const float* __restrict__ b3,
                        float* __restrict__ out, int N) {
    __shared__ unsigned srt[BK_CAP];
    __shared__ int offs[BK_NODES + 1];
    int t = threadIdx.x, b = blockIdx.x;
    if (t < BK_NODES + 1) offs[t] = offs_g[b * (BK_NODES + 1) + t];
    __syncthreads();
    int cnt = offs[BK_NODES];
    const unsigned* sg = srt_g + (size_t)b * BK_CAP;
    int c4 = cnt & ~3;
    for (int i = t * 4; i < c4; i += 2048)
        *reinterpret_cast<uint4*>(&srt[i]) = *reinterpret_cast<const uint4*>(sg + i);
    for (int i = c4 + t; i < cnt; i += 512) srt[i] = sg[i];
    __syncthreads();
    int wv = t >> 6, lane = t & 63;
    int es = lane >> 2, cg = lane & 3;    // 16 edge slots x 4 ch-groups (4ch ea)
    const unsigned short* Hc = H + cg * 4;
    for (int nd = wv; nd < BK_NODES; nd += 8) {
        int d = b * BK_NODES + nd;
        if (d >= N) break;
        int o0 = offs[nd], o1 = offs[nd + 1];
        uint2 sv = {0, 0};
        float dv = 0.f;
        if (es == 0) {
            sv = *reinterpret_cast<const uint2*>(Hc + (size_t)d * 16);
            dv = dinv[d];
        }
        float a0 = 0.f, a1 = 0.f, a2 = 0.f, a3 = 0.f;
        int e = o0 + es;
        for (; e + 16 < o1; e += 32) {    // two independent gathers in flight
            int s0 = srt[e], s1 = srt[e + 16];
            const uint2 v0 = *reinterpret_cast<const uint2*>(Hc + (size_t)s0 * 16);
            const uint2 v1 = *reinterpret_cast<const uint2*>(Hc + (size_t)s1 * 16);
            a0 += bf_lo(v0.x) + bf_lo(v1.x); a1 += bf_hi(v0.x) + bf_hi(v1.x);
            a2 += bf_lo(v0.y) + bf_lo(v1.y); a3 += bf_hi(v0.y) + bf_hi(v1.y);
        }
        if (e < o1) {
            int s0 = srt[e];
            const uint2 v0 = *reinterpret_cast<const uint2*>(Hc + (size_t)s0 * 16);
            a0 += bf_lo(v0.x); a1 += bf_hi(v0.x);
            a2 += bf_lo(v0.y); a3 += bf_hi(v0.y);
        }
#pragma unroll
        for (int m = 4; m <= 32; m <<= 1) {
            a0 += __shfl_xor(a0, m); a1 += __shfl_xor(a1, m);
            a2 += __shfl_xor(a2, m); a3 += __shfl_xor(a3, m);
        }
        if (es == 0) {
            float s[4] = {bf_lo(sv.x), bf_hi(sv.x), bf_lo(sv.y), bf_hi(sv.y)};
            float ac[4] = {a0, a1, a2, a3};
#pragma unroll
            for (int j = 0; j < 4; j++) {
                int ch = cg * 4 + j;
                if (ch < 10)
                    out[(size_t)d * 10 + ch] = dv * (ac[j] + s[j]) + b3[ch];
            }
        }
    }
}

extern "C" void kernel_launch(void* const* d_in, const int* in_sizes, int n_in,
                              void* d_out, int out_size, void* d_ws, size_t ws_size,
                              hipStream_t stream) {
    const float* x  = (const float*)d_in[0];
    const int*   ei = (const int*)d_in[1];
    const float* W1 = (const float*)d_in[2];
    const float* b1 = (const float*)d_in[3];
    const float* W2 = (const float*)d_in[4];
    const float* b2 = (const float*)d_in[5];
    const float* W3 = (const float*)d_in[6];
    const float* b3 = (const float*)d_in[7];

    int N = in_sizes[0] / 128;
    int E = in_sizes[1] / 2;
    const int* esrc = ei;
    const int* edst = ei + E;
    int nb = (N + BK_NODES - 1) >> BK_SHIFT;

    char* p = (char*)d_ws;
    auto carve = [&](size_t bytes) -> void* {
        void* r = p;
        p += (bytes + 255) & ~(size_t)255;
        return r;
    };
    int*      cursor = (int*)carve((size_t)MAXNB * 4);
    unsigned* inter  = (unsigned*)carve((size_t)nb * BK_CAP * 4);
    unsigned* srt_g  = (unsigned*)carve((size_t)nb * BK_CAP * 4);
    int*      offs_g = (int*)carve((size_t)nb * (BK_NODES + 1) * 4);
    float*    dinv   = (float*)carve((size_t)N * 4);
    unsigned short* Hs = (unsigned short*)carve((size_t)N * 64 * 2);  // bf16 row-major
    unsigned short* Gb = (unsigned short*)carve((size_t)N * 64 * 2);  // bf16 agg1 out
    float*    Gf     = (float*)carve((size_t)N * 64 * 4);             // f32 agg2 out
    unsigned short* Hs10 = (unsigned short*)carve((size_t)N * 16 * 2);
    (void)ws_size; (void)n_in; (void)out_size;

    hipMemsetAsync(cursor, 0, (size_t)nb * 4, stream);
    k_partition<<<(E + 16383) / 16384, 512, 0, stream>>>(esrc, edst, E, nb, cursor, inter);
    k_sort<<<nb, 512, 0, stream>>>(inter, cursor, srt_g, offs_g, dinv, N);

    // layer 1: Hs = bf16(dinv*(X @ W1)) ; Gb = bf16(relu(Agg(Hs)+b1))
    k_gemmMF<128, true><<<(N + 63) / 64, 256, 0, stream>>>(x, W1, dinv, Hs, N);
    k_agg64<1><<<nb, 512, 0, stream>>>(Hs, srt_g, offs_g, dinv, b1, Gb, N, 1);
    // layer 2: Hs = bf16(dinv*(Gb @ W2)) ; Gf = relu(Agg(Hs)+b2)
    k_gemmMF<64, false><<<(N + 63) / 64, 256, 0, stream>>>(Gb, W2, dinv, Hs, N);
    k_agg64<0><<<nb, 512, 0, stream>>>(Hs, srt_g, offs_g, dinv, b2, Gf, N, 1);
    // layer 3: Hs10 = bf16(dinv*(Gf @ W3)) 16ch-pad ; out = Agg(Hs10) + b3
    k_gemm10<<<(N + 15) / 16, 256, 0, stream>>>(Gf, W3, dinv, Hs10, N);
    k_agg10s<<<nb, 512, 0, stream>>>(Hs10, srt_g, offs_g, dinv, b3, (float*)d_out, N);
}

// Round 17
// 238.719 us; speedup vs baseline: 1.0492x; 1.0439x over previous
//
#include <hip/hip_runtime.h>

// GCN 3-layer. v17 == v14 exactly (session best: 239.7us). Reverts v15/v16's
// falsified layer-3 padding experiments. Structure: bucket partition (rank
// capture, int4 loads) -> one-shot counting sort -> MFMA bf16 GEMMs ->
// row-major 2-deep gather aggregation (hoisted self-row) -> 10ch bf16 L3 path.

constexpr int BK_SHIFT = 6;               // 64 nodes per bucket
constexpr int BK_NODES = 64;
constexpr int BK_CAP   = 2432;            // mean 2048 + 8.5 sigma
constexpr int MAXNB    = 1568;

typedef __attribute__((ext_vector_type(8))) short short8_t;   // 8 bf16
typedef __attribute__((ext_vector_type(4))) float f32x4_t;    // acc frag

__device__ __forceinline__ unsigned short f2bf(float f) {
    unsigned u = __builtin_bit_cast(unsigned, f);
    u += 0x7FFF + ((u >> 16) & 1);        // round to nearest even
    return (unsigned short)(u >> 16);
}
__device__ __forceinline__ unsigned pack2(float lo, float hi) {
    return (unsigned)f2bf(lo) | ((unsigned)f2bf(hi) << 16);
}
__device__ __forceinline__ float bf_lo(unsigned d) {
    return __builtin_bit_cast(float, d << 16);
}
__device__ __forceinline__ float bf_hi(unsigned d) {
    return __builtin_bit_cast(float, d & 0xFFFF0000u);
}
__device__ __forceinline__ float bf1(unsigned short u) {
    return __builtin_bit_cast(float, (unsigned)u << 16);
}

// 512 thr, 16384 edges/block. Single LDS-atomic pass: rank = atomic return.
// meta = bucket(11b) | rank<<11. cursor[] relative (memset-0).
__global__ __launch_bounds__(512) void k_partition(const int* __restrict__ src,
                            const int* __restrict__ dst,
                            int E, int nb, int* __restrict__ cursor,
                            unsigned* __restrict__ inter) {
    __shared__ int lcount[MAXNB];
    __shared__ int gbase[MAXNB];
    int t = threadIdx.x;
    int base = blockIdx.x * 16384;
    for (int i = t; i < MAXNB; i += 512) lcount[i] = 0;
    __syncthreads();
    unsigned rec[32];
    unsigned meta[32];
    int rem = E - base;
    if (rem >= 16384) {                   // fast path: full tile, int4 loads
        const int4* src4 = reinterpret_cast<const int4*>(src + base);
        const int4* dst4 = reinterpret_cast<const int4*>(dst + base);
#pragma unroll
        for (int j = 0; j < 8; j++) {
            int4 s4 = src4[j * 512 + t];
            int4 d4 = dst4[j * 512 + t];
            int ss[4] = {s4.x, s4.y, s4.z, s4.w};
            int dd[4] = {d4.x, d4.y, d4.z, d4.w};
#pragma unroll
            for (int k = 0; k < 4; k++) {
                int b = dd[k] >> BK_SHIFT;
                int r = atomicAdd(&lcount[b], 1);
                rec[j * 4 + k] = (unsigned)ss[k] | ((unsigned)(dd[k] & (BK_NODES - 1)) << 20);
                meta[j * 4 + k] = (unsigned)b | ((unsigned)r << 11);
            }
        }
    } else {                              // tail block: scalar with guards
#pragma unroll
        for (int j = 0; j < 32; j++) {
            int idx = base + j * 512 + t;
            if (idx < E) {
                int s = src[idx], d = dst[idx];
                int b = d >> BK_SHIFT;
                int r = atomicAdd(&lcount[b], 1);
                rec[j] = (unsigned)s | ((unsigned)(d & (BK_NODES - 1)) << 20);
                meta[j] = (unsigned)b | ((unsigned)r << 11);
            } else meta[j] = 0xFFFFFFFFu;
        }
    }
    __syncthreads();
    for (int i = t; i < nb; i += 512) {
        int c = lcount[i];
        gbase[i] = c ? atomicAdd(&cursor[i], c) : 0;
    }
    __syncthreads();
    if (rem >= 16384) {
#pragma unroll
        for (int j = 0; j < 32; j++) {
            int b = meta[j] & 2047;
            int pos = gbase[b] + (int)(meta[j] >> 11);
            if (pos < BK_CAP) inter[(size_t)b * BK_CAP + pos] = rec[j];
        }
    } else {
#pragma unroll
        for (int j = 0; j < 32; j++) {
            if (meta[j] != 0xFFFFFFFFu) {
                int b = meta[j] & 2047;
                int pos = gbase[b] + (int)(meta[j] >> 11);
                if (pos < BK_CAP) inter[(size_t)b * BK_CAP + pos] = rec[j];
            }
        }
    }
}

// per-bucket counting sort -> srt/offs/dinv (done ONCE, reused by all aggs)
__global__ __launch_bounds__(512) void k_sort(const unsigned* __restrict__ inter,
                        const int* __restrict__ cursor,
                        unsigned* __restrict__ srt_g, int* __restrict__ offs_g,
                        float* __restrict__ dinv, int N) {
    __shared__ unsigned raw[BK_CAP];
    __shared__ unsigned srt[BK_CAP];
    __shared__ int hist[BK_NODES];
    __shared__ int offs[BK_NODES + 1];
    __shared__ int cur[BK_NODES];
    int t = threadIdx.x, b = blockIdx.x;
    if (t < BK_NODES) hist[t] = 0;
    __syncthreads();
    int cnt = min(cursor[b], BK_CAP);
    const unsigned* ip = inter + (size_t)b * BK_CAP;
    int c4 = cnt & ~3;
    for (int i = t * 4; i < c4; i += 2048) {
        uint4 r4 = *reinterpret_cast<const uint4*>(ip + i);
        *reinterpret_cast<uint4*>(&raw[i]) = r4;
        atomicAdd(&hist[r4.x >> 20], 1);
        atomicAdd(&hist[r4.y >> 20], 1);
        atomicAdd(&hist[r4.z >> 20], 1);
        atomicAdd(&hist[r4.w >> 20], 1);
    }
    for (int i = c4 + t; i < cnt; i += 512) {
        unsigned r = ip[i];
        raw[i] = r;
        atomicAdd(&hist[r >> 20], 1);
    }
    __syncthreads();
    if (t < BK_NODES) {                   // wave 0: exclusive scan of 64 bins
        int v = hist[t];
        int inc = v;
#pragma unroll
        for (int d = 1; d < 64; d <<= 1) {
            int o = __shfl_up(inc, d);
            if (t >= d) inc += o;
        }
        offs[t + 1] = inc;
        if (t == 0) offs[0] = 0;
        cur[t] = inc - v;
        int d = b * BK_NODES + t;
        if (d < N) dinv[d] = rsqrtf((float)(v + 1));
    }
    __syncthreads();
    for (int i = t; i < cnt; i += 512) {
        unsigned r = raw[i];
        int pos = atomicAdd(&cur[r >> 20], 1);
        srt[pos] = r & 0xFFFFFu;
    }
    __syncthreads();
    unsigned* sg = srt_g + (size_t)b * BK_CAP;
    for (int i = t * 4; i < c4; i += 2048)
        *reinterpret_cast<uint4*>(sg + i) = *reinterpret_cast<const uint4*>(&srt[i]);
    for (int i = c4 + t; i < cnt; i += 512) sg[i] = srt[i];
    if (t < BK_NODES + 1) offs_g[b * (BK_NODES + 1) + t] = offs[t];
}

// ---- MFMA GEMM: Hs_bf16[n,64] = dinv[n]*(X[n,K] @ W[K,64]), row-major out
template <int K, bool IN_F32>
__global__ __launch_bounds__(256) void k_gemmMF(const void* __restrict__ Xv,
                           const float* __restrict__ W,
                           const float* __restrict__ dinv,
                           unsigned short* __restrict__ Y, int n) {
    constexpr int KP = K + 8;
    __shared__ unsigned short Al[64 * KP];
    __shared__ unsigned short Bl[64 * KP];
    int t = threadIdx.x;
    int nb = blockIdx.x * 64;
    if (IN_F32) {
        const float* X = (const float*)Xv;
        for (int i = t * 4; i < 64 * K; i += 1024) {
            int r = i / K, c = i % K;
            int node = nb + r;
            float4 v = {0.f, 0.f, 0.f, 0.f};
            if (node < n) v = *reinterpret_cast<const float4*>(X + (size_t)node * K + c);
            uint2 pk = {pack2(v.x, v.y), pack2(v.z, v.w)};
            *reinterpret_cast<uint2*>(&Al[r * KP + c]) = pk;
        }
    } else {
        const unsigned short* X = (const unsigned short*)Xv;
        for (int i = t * 4; i < 64 * K; i += 1024) {
            int r = i / K, c = i % K;
            int node = nb + r;
            uint2 pk = {0u, 0u};
            if (node < n) pk = *reinterpret_cast<const uint2*>(X + (size_t)node * K + c);
            *reinterpret_cast<uint2*>(&Al[r * KP + c]) = pk;
        }
    }
    {
        int c = t & 63, kb = t >> 6;
        for (int k = kb; k < K; k += 4)
            Bl[c * KP + k] = f2bf(W[k * 64 + c]);
    }
    __syncthreads();
    int w = t >> 6, lane = t & 63;
    int ml = lane & 15, kg = lane >> 4;
    f32x4_t acc[4] = {{0,0,0,0},{0,0,0,0},{0,0,0,0},{0,0,0,0}};
    for (int ks = 0; ks < K / 32; ks++) {
        int ko = ks * 32 + kg * 8;
        short8_t a = *reinterpret_cast<const short8_t*>(&Al[(16 * w + ml) * KP + ko]);
#pragma unroll
        for (int c = 0; c < 4; c++) {
            short8_t b = *reinterpret_cast<const short8_t*>(&Bl[(16 * c + ml) * KP + ko]);
            acc[c] = __builtin_amdgcn_mfma_f32_16x16x32_bf16(a, b, acc[c], 0, 0, 0);
        }
    }
#pragma unroll
    for (int r = 0; r < 4; r++) {
        int grow = nb + 16 * w + kg * 4 + r;
        if (grow < n) {
            float dv = dinv[grow];
#pragma unroll
            for (int c = 0; c < 4; c++)
                Y[(size_t)grow * 64 + 16 * c + ml] = f2bf(dv * acc[c][r]);
        }
    }
}

// ---- GEMM: Hs10_bf16[n,10] = bf16(dinv[n] * (X[n,64] @ W[64,10])) ----
__global__ void k_gemm10(const float* __restrict__ X, const float* __restrict__ W,
                         const float* __restrict__ dinv, unsigned short* __restrict__ Y, int n) {
    __shared__ float ws[64 * 10];
    __shared__ float xs[16 * 64];
    int t = threadIdx.x;
    for (int i = t; i < 640; i += 256) ws[i] = W[i];
    int nb = blockIdx.x * 16;
    for (int i = t; i < 16 * 64; i += 256) {
        int r = i >> 6, c = i & 63;
        int node = nb + r;
        xs[i] = (node < n) ? X[(size_t)node * 64 + c] : 0.f;
    }
    __syncthreads();
    int ns = t >> 4, c = t & 15;
    if (c < 10) {
        float acc = 0.f;
        for (int k = 0; k < 64; k++) acc += xs[ns * 64 + k] * ws[k * 10 + c];
        int node = nb + ns;
        if (node < n) Y[(size_t)node * 10 + c] = f2bf(dinv[node] * acc);
    }
}

// ---- agg 64ch, row-major table, presorted input, 2-deep unroll.
template <int OBF>
__global__ __launch_bounds__(512) void k_agg64(const unsigned short* __restrict__ H,
                        const unsigned* __restrict__ srt_g, const int* __restrict__ offs_g,
                        const float* __restrict__ dinv, const float* __restrict__ bias,
                        void* __restrict__ outv, int N, int relu) {
    __shared__ unsigned srt[BK_CAP];
    __shared__ int offs[BK_NODES + 1];
    int t = threadIdx.x, b = blockIdx.x;
    if (t < BK_NODES + 1) offs[t] = offs_g[b * (BK_NODES + 1) + t];
    __syncthreads();
    int cnt = offs[BK_NODES];
    const unsigned* sg = srt_g + (size_t)b * BK_CAP;
    int c4 = cnt & ~3;
    for (int i = t * 4; i < c4; i += 2048)
        *reinterpret_cast<uint4*>(&srt[i]) = *reinterpret_cast<const uint4*>(sg + i);
    for (int i = c4 + t; i < cnt; i += 512) srt[i] = sg[i];
    __syncthreads();
    int wv = t >> 6, lane = t & 63;
    int esub = lane >> 3, cg = lane & 7;  // 8 edge slots x 8 channel groups
    const unsigned short* Hc = H + (cg << 3);
    for (int nd = wv; nd < BK_NODES; nd += 8) {
        int d = b * BK_NODES + nd;
        if (d >= N) break;
        int o0 = offs[nd], o1 = offs[nd + 1];
        uint4 sv = {0, 0, 0, 0};
        float dv = 0.f;
        if (esub == 0) {                  // hoisted self-row + dinv
            sv = *reinterpret_cast<const uint4*>(Hc + ((size_t)d << 6));
            dv = dinv[d];
        }
        float a0 = 0.f, a1 = 0.f, a2 = 0.f, a3 = 0.f;
        float a4 = 0.f, a5 = 0.f, a6 = 0.f, a7 = 0.f;
        int e = o0 + esub;
        for (; e + 8 < o1; e += 16) {     // two independent gathers in flight
            int s0 = srt[e], s1 = srt[e + 8];
            const uint4 v0 = *reinterpret_cast<const uint4*>(Hc + ((size_t)s0 << 6));
            const uint4 v1 = *reinterpret_cast<const uint4*>(Hc + ((size_t)s1 << 6));
            a0 += bf_lo(v0.x); a1 += bf_hi(v0.x); a2 += bf_lo(v0.y); a3 += bf_hi(v0.y);
            a4 += bf_lo(v0.z); a5 += bf_hi(v0.z); a6 += bf_lo(v0.w); a7 += bf_hi(v0.w);
            a0 += bf_lo(v1.x); a1 += bf_hi(v1.x); a2 += bf_lo(v1.y); a3 += bf_hi(v1.y);
            a4 += bf_lo(v1.z); a5 += bf_hi(v1.z); a6 += bf_lo(v1.w); a7 += bf_hi(v1.w);
        }
        if (e < o1) {
            int s0 = srt[e];
            const uint4 v0 = *reinterpret_cast<const uint4*>(Hc + ((size_t)s0 << 6));
            a0 += bf_lo(v0.x); a1 += bf_hi(v0.x); a2 += bf_lo(v0.y); a3 += bf_hi(v0.y);
            a4 += bf_lo(v0.z); a5 += bf_hi(v0.z); a6 += bf_lo(v0.w); a7 += bf_hi(v0.w);
        }
#pragma unroll
        for (int m = 8; m <= 32; m <<= 1) {
            a0 += __shfl_xor(a0, m); a1 += __shfl_xor(a1, m);
            a2 += __shfl_xor(a2, m); a3 += __shfl_xor(a3, m);
            a4 += __shfl_xor(a4, m); a5 += __shfl_xor(a5, m);
            a6 += __shfl_xor(a6, m); a7 += __shfl_xor(a7, m);
        }
        if (esub == 0) {
            float s[8] = {bf_lo(sv.x), bf_hi(sv.x), bf_lo(sv.y), bf_hi(sv.y),
                          bf_lo(sv.z), bf_hi(sv.z), bf_lo(sv.w), bf_hi(sv.w)};
            float ac[8] = {a0, a1, a2, a3, a4, a5, a6, a7};
            const float* bp = bias + cg * 8;
            float o[8];
#pragma unroll
            for (int j = 0; j < 8; j++) {
                float val = dv * (ac[j] + s[j]) + bp[j];
                if (relu) val = fmaxf(val, 0.f);
                o[j] = val;
            }
            if (OBF) {
                unsigned short* op = (unsigned short*)outv + (size_t)d * 64 + cg * 8;
                uint4 pk = {pack2(o[0], o[1]), pack2(o[2], o[3]),
                            pack2(o[4], o[5]), pack2(o[6], o[7])};
                *reinterpret_cast<uint4*>(op) = pk;
            } else {
                float* op = (float*)outv + (size_t)d * 64 + cg * 8;
                float4 r0 = {o[0], o[1], o[2], o[3]}, r1 = {o[4], o[5], o[6], o[7]};
                *reinterpret_cast<float4*>(op)     = r0;
                *reinterpret_cast<float4*>(op + 4) = r1;
            }
        }
    }
}

// ---- agg 10ch (final, no relu): bf16 table (2MB, L2-resident), 4-deep ----
__global__ __launch_bounds__(512) void k_agg10s(const unsigned short* __restrict__ H,
                        const unsigned* __restrict__ srt_g, const int* __restrict__ offs_g,
                        const float* __restrict__ dinv, const float* __restrict__ b3,
                        float* __restrict__ out, int N) {
    __shared__ unsigned srt[BK_CAP];
    __shared__ int offs[BK_NODES + 1];
    int t = threadIdx.x, b = blockIdx.x;
    if (t < BK_NODES + 1) offs[t] = offs_g[b * (BK_NODES + 1) + t];
    __syncthreads();
    int cnt = offs[BK_NODES];
    const unsigned* sg = srt_g + (size_t)b * BK_CAP;
    int c4 = cnt & ~3;
    for (int i = t * 4; i < c4; i += 2048)
        *reinterpret_cast<uint4*>(&srt[i]) = *reinterpret_cast<const uint4*>(sg + i);
    for (int i = c4 + t; i < cnt; i += 512) srt[i] = sg[i];
    __syncthreads();
    int wv = t >> 6, lane = t & 63;
    int es = lane >> 4, c = lane & 15;    // 4 edge slots x 16 (10 live) ch
    for (int nd = wv; nd < BK_NODES; nd += 8) {
        int d = b * BK_NODES + nd;
        if (d >= N) break;
        int o0 = offs[nd], o1 = offs[nd + 1];
        float acc = 0.f;
        if (c < 10) {
            int e = o0 + es;
            for (; e + 12 < o1; e += 16) {
                int s0 = srt[e], s1 = srt[e + 4], s2 = srt[e + 8], s3 = srt[e + 12];
                acc += (bf1(H[(size_t)s0 * 10 + c]) + bf1(H[(size_t)s1 * 10 + c]))
                     + (bf1(H[(size_t)s2 * 10 + c]) + bf1(H[(size_t)s3 * 10 + c]));
            }
            for (; e < o1; e += 4) acc += bf1(H[(size_t)srt[e] * 10 + c]);
        }
        acc += __shfl_xor(acc, 16);
        acc += __shfl_xor(acc, 32);
        if (es == 0 && c < 10) {
            float dv = dinv[d];
            out[(size_t)d * 10 + c] = dv * (acc + bf1(H[(size_t)d * 10 + c])) + b3[c];
        }
    }
}

extern "C" void kernel_launch(void* const* d_in, const int* in_sizes, int n_in,
                              void* d_out, int out_size, void* d_ws, size_t ws_size,
                              hipStream_t stream) {
    const float* x  = (const float*)d_in[0];
    const int*   ei = (const int*)d_in[1];
    const float* W1 = (const float*)d_in[2];
    const float* b1 = (const float*)d_in[3];
    const float* W2 = (const float*)d_in[4];
    const float* b2 = (const float*)d_in[5];
    const float* W3 = (const float*)d_in[6];
    const float* b3 = (const float*)d_in[7];

    int N = in_sizes[0] / 128;
    int E = in_sizes[1] / 2;
    const int* esrc = ei;
    const int* edst = ei + E;
    int nb = (N + BK_NODES - 1) >> BK_SHIFT;

    char* p = (char*)d_ws;
    auto carve = [&](size_t bytes) -> void* {
        void* r = p;
        p += (bytes + 255) & ~(size_t)255;
        return r;
    };
    int*      cursor = (int*)carve((size_t)MAXNB * 4);
    unsigned* inter  = (unsigned*)carve((size_t)nb * BK_CAP * 4);
    unsigned* srt_g  = (unsigned*)carve((size_t)nb * BK_CAP * 4);
    int*      offs_g = (int*)carve((size_t)nb * (BK_NODES + 1) * 4);
    float*    dinv   = (float*)carve((size_t)N * 4);
    unsigned short* Hs = (unsigned short*)carve((size_t)N * 64 * 2);  // bf16 row-major
    unsigned short* Gb = (unsigned short*)carve((size_t)N * 64 * 2);  // bf16 agg1 out
    float*    Gf     = (float*)carve((size_t)N * 64 * 4);             // f32 agg2 out
    unsigned short* Hs10 = (unsigned short*)carve((size_t)N * 10 * 2);
    (void)ws_size; (void)n_in; (void)out_size;

    hipMemsetAsync(cursor, 0, (size_t)nb * 4, stream);
    k_partition<<<(E + 16383) / 16384, 512, 0, stream>>>(esrc, edst, E, nb, cursor, inter);
    k_sort<<<nb, 512, 0, stream>>>(inter, cursor, srt_g, offs_g, dinv, N);

    // layer 1: Hs = bf16(dinv*(X @ W1)) ; Gb = bf16(relu(Agg(Hs)+b1))
    k_gemmMF<128, true><<<(N + 63) / 64, 256, 0, stream>>>(x, W1, dinv, Hs, N);
    k_agg64<1><<<nb, 512, 0, stream>>>(Hs, srt_g, offs_g, dinv, b1, Gb, N, 1);
    // layer 2: Hs = bf16(dinv*(Gb @ W2)) ; Gf = relu(Agg(Hs)+b2)
    k_gemmMF<64, false><<<(N + 63) / 64, 256, 0, stream>>>(Gb, W2, dinv, Hs, N);
    k_agg64<0><<<nb, 512, 0, stream>>>(Hs, srt_g, offs_g, dinv, b2, Gf, N, 1);
    // layer 3: Hs10 = bf16(dinv*(Gf @ W3)) ; out = Agg(Hs10) + b3
    k_gemm10<<<(N + 15) / 16, 256, 0, stream>>>(Gf, W3, dinv, Hs10, N);
    k_agg10s<<<nb, 512, 0, stream>>>(Hs10, srt_g, offs_g, dinv, b3, (float*)d_out, N);
}